// Round 1
// baseline (5097.081 us; speedup 1.0000x reference)
//
#include <hip/hip_runtime.h>

#define DIM    384
#define DIM_Q  192
#define HEADS  8
#define HEAD_D 24
#define BATCH  4
#define HH     256
#define WW     256
#define NWIN   32
#define KVP    17                      /* kvbuf row stride (padded vs 16) */
#define SCALE  0.20412414523193154f    /* 24^-0.5 */

// One workgroup (256 threads) per 8x8 spatial tile of one batch image.
// Phases:
//  1. For each of 4 channel groups g (96 ch): stage x chunk (96x64) to LDS,
//     accumulate q partials (192x64, registers), compute kv rows [96g,96g+96)
//     x 16 downsampled positions via on-the-fly DWT (Hadamard of 2x2 block).
//  2. M[h] = SCALE * k_h^T v_h  (24x24 per head) from kv in LDS.
//  3/4. Two rounds of 96 channels each (heads 0-3, then 4-7):
//     spill q half -> feat = q @ M -> spill feat -> accumulate proj partial.
//     Halving qbuf (48KB -> 24KB) brings LDS to 73.5KB => 2 blocks/CU
//     (was 96KB => 1 block/CU, OccupancyPercent 11.9, pure latency-bound).
__global__ __launch_bounds__(256, 2) void wave_attn_fused(
    const float* __restrict__ x, const float* __restrict__ q_w,
    const float* __restrict__ kv_w, const float* __restrict__ proj_w,
    const float* __restrict__ proj_b, float* __restrict__ out)
{
    __shared__ float qbuf[96 * 64];      // 24 KB: half of q rows; reused for feat
    __shared__ float kvbuf[DIM * KVP];   // 25.5 KB: rows 0..191 = k, 192..383 = v
    __shared__ float xs[96 * 64];        // 24 KB: x chunk; reused for M (4608 floats)
    float* mbuf = xs;                    // alias, valid after phase 1

    const int t = threadIdx.x;
    // XCD-bijective swizzle: grid=4096, 8 XCDs -> XCD i owns 512 contiguous
    // tiles (half an image). Neighboring 8-wide tiles then share 64B x-lines
    // in the same L2 instead of re-fetching from HBM.
    const int blk = ((int)blockIdx.x & 7) * 512 + ((int)blockIdx.x >> 3);
    const int b   = blk >> 10;
    const int wy  = (blk >> 5) & 31;
    const int wx  = blk & 31;
    const int by  = wy * 8, bx = wx * 8;

    const int tx = t & 15;   // position group: positions tx*4 .. tx*4+3
    const int ty = t >> 4;   // [0,16)

    // kv assignment: 16 positions (4x4) x 96 rows; thread = (pos=tx, rowblk=ty)
    const int i2 = (tx >> 2) * 2;   // local row of top-left of 2x2 block
    const int j2 = (tx & 3) * 2;    // local col

    float4 accq[12];
#pragma unroll
    for (int i = 0; i < 12; ++i) accq[i] = make_float4(0.f, 0.f, 0.f, 0.f);

    for (int g = 0; g < 4; ++g) {
        // ---- stage x chunk: channels [96g, 96g+96), 8x8 spatial ----
#pragma unroll
        for (int k = 0; k < 6; ++k) {
            int idx = t + (k << 8);          // [0,1536)
            int f  = idx & 1;
            int pi = (idx >> 1) & 7;
            int cl = idx >> 4;               // [0,96)
            const float4 v = *(const float4*)(
                x + (((size_t)(b * DIM + g * 96 + cl) * HH + by + pi) * WW + bx + f * 4));
            *(float4*)&xs[cl * 64 + pi * 8 + f * 4] = v;
        }
        __syncthreads();

        // ---- q partial: q[o, p] += q_w[o, 96g+c] * x[c, p] ----
        for (int c4 = 0; c4 < 24; ++c4) {
            const float4 xv0 = *(const float4*)&xs[(c4 * 4 + 0) * 64 + tx * 4];
            const float4 xv1 = *(const float4*)&xs[(c4 * 4 + 1) * 64 + tx * 4];
            const float4 xv2 = *(const float4*)&xs[(c4 * 4 + 2) * 64 + tx * 4];
            const float4 xv3 = *(const float4*)&xs[(c4 * 4 + 3) * 64 + tx * 4];
#pragma unroll
            for (int i = 0; i < 12; ++i) {
                const float4 w = *(const float4*)(q_w + (ty + 16 * i) * DIM + g * 96 + c4 * 4);
                accq[i].x += w.x * xv0.x + w.y * xv1.x + w.z * xv2.x + w.w * xv3.x;
                accq[i].y += w.x * xv0.y + w.y * xv1.y + w.z * xv2.y + w.w * xv3.y;
                accq[i].z += w.x * xv0.z + w.y * xv1.z + w.z * xv2.z + w.w * xv3.z;
                accq[i].w += w.x * xv0.w + w.y * xv1.w + w.z * xv2.w + w.w * xv3.w;
            }
        }

        // ---- kv rows for this group: on-the-fly DWT ----
        {
            float acck[6] = {0.f, 0.f, 0.f, 0.f, 0.f, 0.f};
            for (int cl = 0; cl < 96; ++cl) {
                const float2 ab = *(const float2*)&xs[cl * 64 + i2 * 8 + j2];
                const float2 cd = *(const float2*)&xs[cl * 64 + (i2 + 1) * 8 + j2];
                const float a  = ab.x, bb = ab.y;
                const float cv = cd.x, dv = cd.y;
                const float ll = 0.5f * (a + bb + cv + dv);
                const float lh = 0.5f * (cv + dv - a - bb);
                const float hl = 0.5f * (bb + dv - a - cv);
                const float hh = 0.5f * (a + dv - bb - cv);
#pragma unroll
                for (int rr = 0; rr < 6; ++rr) {
                    const float4 w = *(const float4*)(kv_w + (g * 96 + ty * 6 + rr) * DIM + cl * 4);
                    acck[rr] += w.x * ll + w.y * lh + w.z * hl + w.w * hh;
                }
            }
#pragma unroll
            for (int rr = 0; rr < 6; ++rr)
                kvbuf[(g * 96 + ty * 6 + rr) * KVP + tx] = acck[rr];
        }
        __syncthreads();   // xs reuse next iter; kvbuf complete for this group
    }

    // ---- phase 2: M[h][d1][d2] = SCALE * sum_p k[h*24+d1,p] * v[h*24+d2,p] ----
    // kvbuf stride 17 -> the stride-16 32-way bank conflict on kvals reads is gone.
    if (t < DIM_Q) {
        const int h = t / 24, d1 = t % 24;
        float kvals[16];
#pragma unroll
        for (int p = 0; p < 16; ++p) kvals[p] = kvbuf[t * KVP + p];
        for (int d2 = 0; d2 < 24; ++d2) {
            float s = 0.f;
#pragma unroll
            for (int p = 0; p < 16; ++p)
                s += kvals[p] * kvbuf[(DIM_Q + h * 24 + d2) * KVP + p];
            mbuf[(h * 24 + d1) * 24 + d2] = SCALE * s;
        }
    }
    __syncthreads();

    // ---- phases 3+4 in two rounds of 96 channels (4 heads each) ----
    float4 acco[24];
#pragma unroll
    for (int i = 0; i < 24; ++i) acco[i] = make_float4(0.f, 0.f, 0.f, 0.f);

#pragma unroll
    for (int r = 0; r < 2; ++r) {
        // spill q rows [96r, 96r+96) to qbuf (local row = global - 96r)
#pragma unroll
        for (int ii = 0; ii < 6; ++ii)
            *(float4*)&qbuf[(ty + 16 * ii) * 64 + tx * 4] = accq[ii + 6 * r];
        __syncthreads();

        // feat[ch, p] = sum_d' q[h*24+d', p] * M[h][d'][ch%24], ch in this half
        float4 featacc[6];
#pragma unroll
        for (int ii = 0; ii < 6; ++ii) {
            const int ch = 96 * r + ty + 16 * ii;
            const int h  = ch / 24, d = ch % 24;
            const int hl = (h - 4 * r) * 24;      // local q row base in qbuf
            float4 acc = make_float4(0.f, 0.f, 0.f, 0.f);
            for (int dp = 0; dp < 24; ++dp) {
                const float4 qv = *(const float4*)&qbuf[(hl + dp) * 64 + tx * 4];
                const float m = mbuf[(h * 24 + dp) * 24 + d];
                acc.x += m * qv.x; acc.y += m * qv.y;
                acc.z += m * qv.z; acc.w += m * qv.w;
            }
            featacc[ii] = acc;
        }
        __syncthreads();   // all q reads done before overwrite
#pragma unroll
        for (int ii = 0; ii < 6; ++ii)
            *(float4*)&qbuf[(ty + 16 * ii) * 64 + tx * 4] = featacc[ii];
        __syncthreads();

        // proj partial over this half: out[o,p] += proj_w[o, 96r+c] * feat[c,p]
        for (int c4 = 0; c4 < 24; ++c4) {
            const float4 f0 = *(const float4*)&qbuf[(c4 * 4 + 0) * 64 + tx * 4];
            const float4 f1 = *(const float4*)&qbuf[(c4 * 4 + 1) * 64 + tx * 4];
            const float4 f2 = *(const float4*)&qbuf[(c4 * 4 + 2) * 64 + tx * 4];
            const float4 f3 = *(const float4*)&qbuf[(c4 * 4 + 3) * 64 + tx * 4];
#pragma unroll
            for (int i = 0; i < 24; ++i) {
                const float4 w = *(const float4*)(proj_w + (ty + 16 * i) * DIM_Q + 96 * r + c4 * 4);
                acco[i].x += w.x * f0.x + w.y * f1.x + w.z * f2.x + w.w * f3.x;
                acco[i].y += w.x * f0.y + w.y * f1.y + w.z * f2.y + w.w * f3.y;
                acco[i].z += w.x * f0.z + w.y * f1.z + w.z * f2.z + w.w * f3.z;
                acco[i].w += w.x * f0.w + w.y * f1.w + w.z * f2.w + w.w * f3.w;
            }
        }
        __syncthreads();   // feat reads done before next round's q spill
    }

    // ---- epilogue: bias + store ----
    const int pi = tx >> 1;
    const int pj = (tx & 1) * 4;
#pragma unroll
    for (int i = 0; i < 24; ++i) {
        const int o = ty + 16 * i;
        const float bias = proj_b[o];
        float4 r = acco[i];
        r.x += bias; r.y += bias; r.z += bias; r.w += bias;
        *(float4*)(out + (((size_t)(b * DIM + o) * HH + by + pi) * WW + bx + pj)) = r;
    }
}

extern "C" void kernel_launch(void* const* d_in, const int* in_sizes, int n_in,
                              void* d_out, int out_size, void* d_ws, size_t ws_size,
                              hipStream_t stream) {
    const float* x      = (const float*)d_in[0];
    const float* q_w    = (const float*)d_in[1];
    const float* kv_w   = (const float*)d_in[2];
    const float* proj_w = (const float*)d_in[3];
    const float* proj_b = (const float*)d_in[4];
    float* out = (float*)d_out;
    (void)in_sizes; (void)n_in; (void)out_size; (void)d_ws; (void)ws_size;

    dim3 grid(BATCH * NWIN * NWIN);   // 4096 tiles
    dim3 block(256);
    hipLaunchKernelGGL(wave_attn_fused, grid, block, 0, stream,
                       x, q_w, kv_w, proj_w, proj_b, out);
}

// Round 2
// 3492.142 us; speedup vs baseline: 1.4596x; 1.4596x over previous
//
#include <hip/hip_runtime.h>

#define DIM    384
#define DIM_Q  192
#define HEADS  8
#define HEAD_D 24
#define BATCH  4
#define HH     256
#define WW     256
#define NWIN   32
#define KVP    17                      /* kvbuf row stride (padded vs 16) */
#define SCALE  0.20412414523193154f    /* 24^-0.5 */

// One workgroup (256 threads) per 8x8 spatial tile of one batch image.
// Phases:
//  1. For each of 4 channel groups g (96 ch): stage x chunk (96x64) to LDS,
//     accumulate q partials (192x64, registers), compute kv rows [96g,96g+96)
//     x 16 downsampled positions via on-the-fly DWT (Hadamard of 2x2 block).
//  2. M[h] = SCALE * k_h^T v_h  (24x24 per head) from kv in LDS.
//  3/4. Two rounds of 96 channels each (heads 0-3, then 4-7):
//     spill q half -> feat = q @ M -> spill feat -> accumulate proj partial.
//     LDS = 73.5 KB => 2 blocks/CU (LDS-limited, was 96 KB => 1 block/CU).
// NOTE: __launch_bounds__(256) ONLY — adding ",2" caps VGPR at 128 and the
// accumulator live set (acco[24] float4 = 96 regs) spills to scratch:
// measured +4.5 GB HBM spill traffic, 5170 us vs 3585. VGPR<=256 already
// gives the 2 waves/SIMD needed for 2 blocks/CU; LDS is the binding limit.
__global__ __launch_bounds__(256) void wave_attn_fused(
    const float* __restrict__ x, const float* __restrict__ q_w,
    const float* __restrict__ kv_w, const float* __restrict__ proj_w,
    const float* __restrict__ proj_b, float* __restrict__ out)
{
    __shared__ float qbuf[96 * 64];      // 24 KB: half of q rows; reused for feat
    __shared__ float kvbuf[DIM * KVP];   // 25.5 KB: rows 0..191 = k, 192..383 = v
    __shared__ float xs[96 * 64];        // 24 KB: x chunk; reused for M (4608 floats)
    float* mbuf = xs;                    // alias, valid after phase 1

    const int t = threadIdx.x;
    // XCD-bijective swizzle: grid=4096, 8 XCDs -> XCD i owns 512 contiguous
    // tiles (half an image). Neighboring 8-wide tiles then share 64B x-lines
    // in the same L2 instead of re-fetching from HBM.
    const int blk = ((int)blockIdx.x & 7) * 512 + ((int)blockIdx.x >> 3);
    const int b   = blk >> 10;
    const int wy  = (blk >> 5) & 31;
    const int wx  = blk & 31;
    const int by  = wy * 8, bx = wx * 8;

    const int tx = t & 15;   // position group: positions tx*4 .. tx*4+3
    const int ty = t >> 4;   // [0,16)

    // kv assignment: 16 positions (4x4) x 96 rows; thread = (pos=tx, rowblk=ty)
    const int i2 = (tx >> 2) * 2;   // local row of top-left of 2x2 block
    const int j2 = (tx & 3) * 2;    // local col

    float4 accq[12];
#pragma unroll
    for (int i = 0; i < 12; ++i) accq[i] = make_float4(0.f, 0.f, 0.f, 0.f);

    for (int g = 0; g < 4; ++g) {
        // ---- stage x chunk: channels [96g, 96g+96), 8x8 spatial ----
#pragma unroll
        for (int k = 0; k < 6; ++k) {
            int idx = t + (k << 8);          // [0,1536)
            int f  = idx & 1;
            int pi = (idx >> 1) & 7;
            int cl = idx >> 4;               // [0,96)
            const float4 v = *(const float4*)(
                x + (((size_t)(b * DIM + g * 96 + cl) * HH + by + pi) * WW + bx + f * 4));
            *(float4*)&xs[cl * 64 + pi * 8 + f * 4] = v;
        }
        __syncthreads();

        // ---- q partial: q[o, p] += q_w[o, 96g+c] * x[c, p] ----
        for (int c4 = 0; c4 < 24; ++c4) {
            const float4 xv0 = *(const float4*)&xs[(c4 * 4 + 0) * 64 + tx * 4];
            const float4 xv1 = *(const float4*)&xs[(c4 * 4 + 1) * 64 + tx * 4];
            const float4 xv2 = *(const float4*)&xs[(c4 * 4 + 2) * 64 + tx * 4];
            const float4 xv3 = *(const float4*)&xs[(c4 * 4 + 3) * 64 + tx * 4];
#pragma unroll
            for (int i = 0; i < 12; ++i) {
                const float4 w = *(const float4*)(q_w + (ty + 16 * i) * DIM + g * 96 + c4 * 4);
                accq[i].x += w.x * xv0.x + w.y * xv1.x + w.z * xv2.x + w.w * xv3.x;
                accq[i].y += w.x * xv0.y + w.y * xv1.y + w.z * xv2.y + w.w * xv3.y;
                accq[i].z += w.x * xv0.z + w.y * xv1.z + w.z * xv2.z + w.w * xv3.z;
                accq[i].w += w.x * xv0.w + w.y * xv1.w + w.z * xv2.w + w.w * xv3.w;
            }
        }

        // ---- kv rows for this group: on-the-fly DWT ----
        {
            float acck[6] = {0.f, 0.f, 0.f, 0.f, 0.f, 0.f};
            for (int cl = 0; cl < 96; ++cl) {
                const float2 ab = *(const float2*)&xs[cl * 64 + i2 * 8 + j2];
                const float2 cd = *(const float2*)&xs[cl * 64 + (i2 + 1) * 8 + j2];
                const float a  = ab.x, bb = ab.y;
                const float cv = cd.x, dv = cd.y;
                const float ll = 0.5f * (a + bb + cv + dv);
                const float lh = 0.5f * (cv + dv - a - bb);
                const float hl = 0.5f * (bb + dv - a - cv);
                const float hh = 0.5f * (a + dv - bb - cv);
#pragma unroll
                for (int rr = 0; rr < 6; ++rr) {
                    const float4 w = *(const float4*)(kv_w + (g * 96 + ty * 6 + rr) * DIM + cl * 4);
                    acck[rr] += w.x * ll + w.y * lh + w.z * hl + w.w * hh;
                }
            }
#pragma unroll
            for (int rr = 0; rr < 6; ++rr)
                kvbuf[(g * 96 + ty * 6 + rr) * KVP + tx] = acck[rr];
        }
        __syncthreads();   // xs reuse next iter; kvbuf complete for this group
    }

    // ---- phase 2: M[h][d1][d2] = SCALE * sum_p k[h*24+d1,p] * v[h*24+d2,p] ----
    // kvbuf stride 17 -> the stride-16 32-way bank conflict on kvals reads is gone.
    if (t < DIM_Q) {
        const int h = t / 24, d1 = t % 24;
        float kvals[16];
#pragma unroll
        for (int p = 0; p < 16; ++p) kvals[p] = kvbuf[t * KVP + p];
        for (int d2 = 0; d2 < 24; ++d2) {
            float s = 0.f;
#pragma unroll
            for (int p = 0; p < 16; ++p)
                s += kvals[p] * kvbuf[(DIM_Q + h * 24 + d2) * KVP + p];
            mbuf[(h * 24 + d1) * 24 + d2] = SCALE * s;
        }
    }
    __syncthreads();

    // ---- phases 3+4 in two rounds of 96 channels (4 heads each) ----
    float4 acco[24];
#pragma unroll
    for (int i = 0; i < 24; ++i) acco[i] = make_float4(0.f, 0.f, 0.f, 0.f);

#pragma unroll
    for (int r = 0; r < 2; ++r) {
        // spill q rows [96r, 96r+96) to qbuf (local row = global - 96r)
#pragma unroll
        for (int ii = 0; ii < 6; ++ii)
            *(float4*)&qbuf[(ty + 16 * ii) * 64 + tx * 4] = accq[ii + 6 * r];
        __syncthreads();

        // feat[ch, p] = sum_d' q[h*24+d', p] * M[h][d'][ch%24], ch in this half
        float4 featacc[6];
#pragma unroll
        for (int ii = 0; ii < 6; ++ii) {
            const int ch = 96 * r + ty + 16 * ii;
            const int h  = ch / 24, d = ch % 24;
            const int hl = (h - 4 * r) * 24;      // local q row base in qbuf
            float4 acc = make_float4(0.f, 0.f, 0.f, 0.f);
            for (int dp = 0; dp < 24; ++dp) {
                const float4 qv = *(const float4*)&qbuf[(hl + dp) * 64 + tx * 4];
                const float m = mbuf[(h * 24 + dp) * 24 + d];
                acc.x += m * qv.x; acc.y += m * qv.y;
                acc.z += m * qv.z; acc.w += m * qv.w;
            }
            featacc[ii] = acc;
        }
        __syncthreads();   // all q reads done before overwrite
#pragma unroll
        for (int ii = 0; ii < 6; ++ii)
            *(float4*)&qbuf[(ty + 16 * ii) * 64 + tx * 4] = featacc[ii];
        __syncthreads();

        // proj partial over this half: out[o,p] += proj_w[o, 96r+c] * feat[c,p]
        for (int c4 = 0; c4 < 24; ++c4) {
            const float4 f0 = *(const float4*)&qbuf[(c4 * 4 + 0) * 64 + tx * 4];
            const float4 f1 = *(const float4*)&qbuf[(c4 * 4 + 1) * 64 + tx * 4];
            const float4 f2 = *(const float4*)&qbuf[(c4 * 4 + 2) * 64 + tx * 4];
            const float4 f3 = *(const float4*)&qbuf[(c4 * 4 + 3) * 64 + tx * 4];
#pragma unroll
            for (int i = 0; i < 24; ++i) {
                const float4 w = *(const float4*)(proj_w + (ty + 16 * i) * DIM_Q + 96 * r + c4 * 4);
                acco[i].x += w.x * f0.x + w.y * f1.x + w.z * f2.x + w.w * f3.x;
                acco[i].y += w.x * f0.y + w.y * f1.y + w.z * f2.y + w.w * f3.y;
                acco[i].z += w.x * f0.z + w.y * f1.z + w.z * f2.z + w.w * f3.z;
                acco[i].w += w.x * f0.w + w.y * f1.w + w.z * f2.w + w.w * f3.w;
            }
        }
        __syncthreads();   // feat reads done before next round's q spill
    }

    // ---- epilogue: bias + store ----
    const int pi = tx >> 1;
    const int pj = (tx & 1) * 4;
#pragma unroll
    for (int i = 0; i < 24; ++i) {
        const int o = ty + 16 * i;
        const float bias = proj_b[o];
        float4 r = acco[i];
        r.x += bias; r.y += bias; r.z += bias; r.w += bias;
        *(float4*)(out + (((size_t)(b * DIM + o) * HH + by + pi) * WW + bx + pj)) = r;
    }
}

extern "C" void kernel_launch(void* const* d_in, const int* in_sizes, int n_in,
                              void* d_out, int out_size, void* d_ws, size_t ws_size,
                              hipStream_t stream) {
    const float* x      = (const float*)d_in[0];
    const float* q_w    = (const float*)d_in[1];
    const float* kv_w   = (const float*)d_in[2];
    const float* proj_w = (const float*)d_in[3];
    const float* proj_b = (const float*)d_in[4];
    float* out = (float*)d_out;
    (void)in_sizes; (void)n_in; (void)out_size; (void)d_ws; (void)ws_size;

    dim3 grid(BATCH * NWIN * NWIN);   // 4096 tiles
    dim3 block(256);
    hipLaunchKernelGGL(wave_attn_fused, grid, block, 0, stream,
                       x, q_w, kv_w, proj_w, proj_b, out);
}

// Round 3
// 2924.349 us; speedup vs baseline: 1.7430x; 1.1942x over previous
//
#include <hip/hip_runtime.h>

#define DIM    384
#define DIM_Q  192
#define BATCH  4
#define HH     256
#define WW     256
#define KVP    17                      /* kvbuf row stride (padded vs 16) */
#define SCALE  0.20412414523193154f    /* 24^-0.5 */

// One 512-thread workgroup (8 waves) per 8x8 spatial tile of one batch image.
// OCCUPANCY HISTORY: 256-thread blocks needed ~150-224 VGPR/thread -> only
// 1 block/CU resident -> 1 wave/SIMD (OccupancyPercent ~12, VALUBusy ~48,
// pure latency-bound). launch_bounds(256,2) forced VGPR=128 and spilled
// 4.5 GB to scratch (5170 us). Fix: 512-thread block -- its 8 waves are
// co-resident BY CONSTRUCTION (2 waves/SIMD), per-thread accumulators halve
// (acco[12]=48 regs, accq[6]=24 regs, peak live ~90), no cap needed.
// LDS 145.5 KB single block: full qbuf + separate feat buffer (no 2-round
// split). DWT is hoisted out of the kv loop (was recomputed 32x per value)
// into one in-place LDS pass: region [cl*64+16m, +16) is closed under the
// transform -> one thread per region, no cross-thread hazard.
__global__ __launch_bounds__(512) void wave_attn_fused(
    const float* __restrict__ x, const float* __restrict__ q_w,
    const float* __restrict__ kv_w, const float* __restrict__ proj_w,
    const float* __restrict__ proj_b, float* __restrict__ out)
{
    __shared__ float qbuf[DIM_Q * 64];   // 48 KB: q rows 0..191, stride 64
    __shared__ float fbuf[DIM_Q * 64];   // 48 KB: feat
    __shared__ float kvbuf[DIM * KVP];   // 25.5 KB: rows 0..191 k, 192..383 v
    __shared__ float xs[96 * 64];        // 24 KB: x chunk -> dwt (in place) -> M
    float* mbuf = xs;                    // alias, valid after phase 1 (4608 floats)

    const int t = threadIdx.x;
    // XCD-bijective swizzle (grid 4096 % 8 == 0): each XCD owns 512 contiguous
    // tiles -> neighboring tiles share x cache lines in the same L2.
    // Measured: FETCH_SIZE 860 MB -> 271 MB. Keep.
    const int blk = ((int)blockIdx.x & 7) * 512 + ((int)blockIdx.x >> 3);
    const int b   = blk >> 10;
    const int wy  = (blk >> 5) & 31;
    const int wx  = blk & 31;
    const int by  = wy * 8, bx = wx * 8;

    const int tx = t & 15;   // position group: positions tx*4 .. tx*4+3
    const int ty = t >> 4;   // [0,32)

    float4 accq[6];
#pragma unroll
    for (int i = 0; i < 6; ++i) accq[i] = make_float4(0.f, 0.f, 0.f, 0.f);

    // ---- prologue: stage x group 0 (channels 0..95, 8x8 spatial) ----
#pragma unroll
    for (int k = 0; k < 3; ++k) {
        const int idx = t + (k << 9);            // [0,1536)
        const int f  = idx & 1;
        const int pi = (idx >> 1) & 7;
        const int cl = idx >> 4;                 // [0,96)
        *(float4*)&xs[cl * 64 + pi * 8 + f * 4] = *(const float4*)(
            x + (((size_t)(b * DIM + cl) * HH + by + pi) * WW + bx + f * 4));
    }
    __syncthreads();

    for (int g = 0; g < 4; ++g) {
        // ---- prefetch next group's x chunk into registers (hides HBM/L2
        //      latency under the q/kv compute below) ----
        float4 pf0, pf1, pf2;
        if (g < 3) {
            {
                const int idx = t;
                const int f = idx & 1, pi = (idx >> 1) & 7, cl = idx >> 4;
                pf0 = *(const float4*)(x + (((size_t)(b * DIM + (g + 1) * 96 + cl) * HH + by + pi) * WW + bx + f * 4));
            }
            {
                const int idx = t + 512;
                const int f = idx & 1, pi = (idx >> 1) & 7, cl = idx >> 4;
                pf1 = *(const float4*)(x + (((size_t)(b * DIM + (g + 1) * 96 + cl) * HH + by + pi) * WW + bx + f * 4));
            }
            {
                const int idx = t + 1024;
                const int f = idx & 1, pi = (idx >> 1) & 7, cl = idx >> 4;
                pf2 = *(const float4*)(x + (((size_t)(b * DIM + (g + 1) * 96 + cl) * HH + by + pi) * WW + bx + f * 4));
            }
        }

        // ---- q partial: q[o, p] += q_w[o, 96g+c] * x[c, p], o = ty+32i ----
        for (int c4 = 0; c4 < 24; ++c4) {
            const float4 xv0 = *(const float4*)&xs[(c4 * 4 + 0) * 64 + tx * 4];
            const float4 xv1 = *(const float4*)&xs[(c4 * 4 + 1) * 64 + tx * 4];
            const float4 xv2 = *(const float4*)&xs[(c4 * 4 + 2) * 64 + tx * 4];
            const float4 xv3 = *(const float4*)&xs[(c4 * 4 + 3) * 64 + tx * 4];
#pragma unroll
            for (int i = 0; i < 6; ++i) {
                const float4 w = *(const float4*)(q_w + (ty + 32 * i) * DIM + g * 96 + c4 * 4);
                accq[i].x += w.x * xv0.x + w.y * xv1.x + w.z * xv2.x + w.w * xv3.x;
                accq[i].y += w.x * xv0.y + w.y * xv1.y + w.z * xv2.y + w.w * xv3.y;
                accq[i].z += w.x * xv0.z + w.y * xv1.z + w.z * xv2.z + w.w * xv3.z;
                accq[i].w += w.x * xv0.w + w.y * xv1.w + w.z * xv2.w + w.w * xv3.w;
            }
        }
        __syncthreads();   // all q reads of original-layout xs done

        // ---- in-place DWT: xs[cl*64 + p'*4 .. +3] := (ll,lh,hl,hh) of the
        //      2x2 block at downsampled position p' = (i2/2)*4 + (j2/2).
        //      One thread per closed 16-word region (cl, row-pair m). ----
        if (t < 384) {
            const int base = (t >> 2) * 64 + (t & 3) * 16;  // cl = t>>2, m = t&3
            const float4 r0a = *(const float4*)&xs[base + 0];   // row i2,  j 0..3
            const float4 r0b = *(const float4*)&xs[base + 4];   // row i2,  j 4..7
            const float4 r1a = *(const float4*)&xs[base + 8];   // row i2+1, j 0..3
            const float4 r1b = *(const float4*)&xs[base + 12];  // row i2+1, j 4..7
            float4 o0, o1, o2, o3;
            // block j2=0: a=r0a.x b=r0a.y c=r1a.x d=r1a.y
            o0.x = 0.5f * ( r0a.x + r0a.y + r1a.x + r1a.y);
            o0.y = 0.5f * (-r0a.x - r0a.y + r1a.x + r1a.y);
            o0.z = 0.5f * (-r0a.x + r0a.y - r1a.x + r1a.y);
            o0.w = 0.5f * ( r0a.x - r0a.y - r1a.x + r1a.y);
            // block j2=2: a=r0a.z b=r0a.w c=r1a.z d=r1a.w
            o1.x = 0.5f * ( r0a.z + r0a.w + r1a.z + r1a.w);
            o1.y = 0.5f * (-r0a.z - r0a.w + r1a.z + r1a.w);
            o1.z = 0.5f * (-r0a.z + r0a.w - r1a.z + r1a.w);
            o1.w = 0.5f * ( r0a.z - r0a.w - r1a.z + r1a.w);
            // block j2=4: a=r0b.x b=r0b.y c=r1b.x d=r1b.y
            o2.x = 0.5f * ( r0b.x + r0b.y + r1b.x + r1b.y);
            o2.y = 0.5f * (-r0b.x - r0b.y + r1b.x + r1b.y);
            o2.z = 0.5f * (-r0b.x + r0b.y - r1b.x + r1b.y);
            o2.w = 0.5f * ( r0b.x - r0b.y - r1b.x + r1b.y);
            // block j2=6: a=r0b.z b=r0b.w c=r1b.z d=r1b.w
            o3.x = 0.5f * ( r0b.z + r0b.w + r1b.z + r1b.w);
            o3.y = 0.5f * (-r0b.z - r0b.w + r1b.z + r1b.w);
            o3.z = 0.5f * (-r0b.z + r0b.w - r1b.z + r1b.w);
            o3.w = 0.5f * ( r0b.z - r0b.w - r1b.z + r1b.w);
            *(float4*)&xs[base + 0]  = o0;
            *(float4*)&xs[base + 4]  = o1;
            *(float4*)&xs[base + 8]  = o2;
            *(float4*)&xs[base + 12] = o3;
        }
        __syncthreads();   // transformed xs visible

        // ---- kv rows ty*3..ty*3+2 of this group: weight cols cl*4+{0..3}
        //      are the 4 subbands of local channel cl (grouped 1x1 conv). ----
        {
            float acck0 = 0.f, acck1 = 0.f, acck2 = 0.f;
            const float* kw = kv_w + (size_t)(g * 96 + ty * 3) * DIM;
            for (int cl = 0; cl < 96; ++cl) {
                const float4 d  = *(const float4*)&xs[cl * 64 + tx * 4];
                const float4 w0 = *(const float4*)(kw + cl * 4);
                const float4 w1 = *(const float4*)(kw + DIM + cl * 4);
                const float4 w2 = *(const float4*)(kw + 2 * DIM + cl * 4);
                acck0 += w0.x * d.x + w0.y * d.y + w0.z * d.z + w0.w * d.w;
                acck1 += w1.x * d.x + w1.y * d.y + w1.z * d.z + w1.w * d.w;
                acck2 += w2.x * d.x + w2.y * d.y + w2.z * d.z + w2.w * d.w;
            }
            kvbuf[(g * 96 + ty * 3 + 0) * KVP + tx] = acck0;
            kvbuf[(g * 96 + ty * 3 + 1) * KVP + tx] = acck1;
            kvbuf[(g * 96 + ty * 3 + 2) * KVP + tx] = acck2;
        }
        __syncthreads();   // xs reads done; kvbuf rows of this group complete

        // ---- write prefetched next group into xs ----
        if (g < 3) {
            {
                const int idx = t;
                const int f = idx & 1, pi = (idx >> 1) & 7, cl = idx >> 4;
                *(float4*)&xs[cl * 64 + pi * 8 + f * 4] = pf0;
            }
            {
                const int idx = t + 512;
                const int f = idx & 1, pi = (idx >> 1) & 7, cl = idx >> 4;
                *(float4*)&xs[cl * 64 + pi * 8 + f * 4] = pf1;
            }
            {
                const int idx = t + 1024;
                const int f = idx & 1, pi = (idx >> 1) & 7, cl = idx >> 4;
                *(float4*)&xs[cl * 64 + pi * 8 + f * 4] = pf2;
            }
            __syncthreads();
        }
    }

    // ---- spill q to qbuf (fresh region; visibility via phase-2 barrier) ----
#pragma unroll
    for (int i = 0; i < 6; ++i)
        *(float4*)&qbuf[(ty + 32 * i) * 64 + tx * 4] = accq[i];

    // ---- phase 2: M[h][d1][d2] = SCALE * sum_p k[h*24+d1,p] * v[h*24+d2,p]
    //      384 threads: (k-row, d2-half) each -> 12 d2 values. ----
    if (t < 384) {
        const int hd1   = t >> 1;          // k-row [0,192)
        const int h     = hd1 / 24;
        const int dbase = (t & 1) * 12;
        float kvals[16];
#pragma unroll
        for (int p = 0; p < 16; ++p) kvals[p] = kvbuf[hd1 * KVP + p];
        const float* vrow = &kvbuf[(DIM_Q + h * 24 + dbase) * KVP];
        for (int d2 = 0; d2 < 12; ++d2) {
            float s = 0.f;
#pragma unroll
            for (int p = 0; p < 16; ++p)
                s += kvals[p] * vrow[d2 * KVP + p];
            mbuf[hd1 * 24 + dbase + d2] = SCALE * s;
        }
    }
    __syncthreads();   // qbuf spill + mbuf visible

    // ---- phase 3: feat[ch, p] = sum_d' q[h*24+d', p] * M[h][d'][ch%24] ----
#pragma unroll
    for (int ii = 0; ii < 6; ++ii) {
        const int ch = ty + 32 * ii;
        const int h = ch / 24, d = ch % 24;
        const float* qrow = &qbuf[h * 24 * 64 + tx * 4];
        const float* mcol = &mbuf[h * 24 * 24 + d];
        float4 acc = make_float4(0.f, 0.f, 0.f, 0.f);
        for (int dp = 0; dp < 24; ++dp) {
            const float4 qv = *(const float4*)(qrow + dp * 64);
            const float  m  = mcol[dp * 24];
            acc.x += m * qv.x; acc.y += m * qv.y;
            acc.z += m * qv.z; acc.w += m * qv.w;
        }
        *(float4*)&fbuf[ch * 64 + tx * 4] = acc;   // separate buffer: no dance
    }
    __syncthreads();

    // ---- phase 4: out[o, p] = proj_b[o] + sum_ch proj_w[o, ch] * feat[ch, p] ----
    float4 acco[12];
#pragma unroll
    for (int i = 0; i < 12; ++i) acco[i] = make_float4(0.f, 0.f, 0.f, 0.f);
    for (int c4 = 0; c4 < 48; ++c4) {
        const float4 f0 = *(const float4*)&fbuf[(c4 * 4 + 0) * 64 + tx * 4];
        const float4 f1 = *(const float4*)&fbuf[(c4 * 4 + 1) * 64 + tx * 4];
        const float4 f2 = *(const float4*)&fbuf[(c4 * 4 + 2) * 64 + tx * 4];
        const float4 f3 = *(const float4*)&fbuf[(c4 * 4 + 3) * 64 + tx * 4];
#pragma unroll
        for (int i = 0; i < 12; ++i) {
            const float4 w = *(const float4*)(proj_w + (ty + 32 * i) * DIM_Q + c4 * 4);
            acco[i].x += w.x * f0.x + w.y * f1.x + w.z * f2.x + w.w * f3.x;
            acco[i].y += w.x * f0.y + w.y * f1.y + w.z * f2.y + w.w * f3.y;
            acco[i].z += w.x * f0.z + w.y * f1.z + w.z * f2.z + w.w * f3.z;
            acco[i].w += w.x * f0.w + w.y * f1.w + w.z * f2.w + w.w * f3.w;
        }
    }

    // ---- epilogue: bias + store ----
    const int pi = tx >> 1;
    const int pj = (tx & 1) * 4;
#pragma unroll
    for (int i = 0; i < 12; ++i) {
        const int o = ty + 32 * i;
        const float bias = proj_b[o];
        float4 r = acco[i];
        r.x += bias; r.y += bias; r.z += bias; r.w += bias;
        *(float4*)(out + (((size_t)(b * DIM + o) * HH + by + pi) * WW + bx + pj)) = r;
    }
}

extern "C" void kernel_launch(void* const* d_in, const int* in_sizes, int n_in,
                              void* d_out, int out_size, void* d_ws, size_t ws_size,
                              hipStream_t stream) {
    const float* x      = (const float*)d_in[0];
    const float* q_w    = (const float*)d_in[1];
    const float* kv_w   = (const float*)d_in[2];
    const float* proj_w = (const float*)d_in[3];
    const float* proj_b = (const float*)d_in[4];
    float* out = (float*)d_out;
    (void)in_sizes; (void)n_in; (void)out_size; (void)d_ws; (void)ws_size;

    dim3 grid(BATCH * 32 * 32);   // 4096 tiles
    dim3 block(512);
    hipLaunchKernelGGL(wave_attn_fused, grid, block, 0, stream,
                       x, q_w, kv_w, proj_w, proj_b, out);
}